// Round 1
// baseline (4509.461 us; speedup 1.0000x reference)
//
#include <hip/hip_runtime.h>

constexpr int C = 1024, H = 256, V = 10000, K = 32, B = 8, T = 256, K1K = 65;

#define DEV static __device__ __forceinline__

DEV unsigned encf(float f) {
  unsigned u = __float_as_uint(f);
  return (u & 0x80000000u) ? ~u : (u | 0x80000000u);
}
DEV float decf(unsigned e) {
  unsigned u = (e & 0x80000000u) ? (e & 0x7fffffffu) : ~e;
  return __uint_as_float(u);
}

// ---------- Menc init: enc(-inf) ----------
__global__ void k_menc_init(unsigned* Menc) {
  int i = blockIdx.x * 256 + threadIdx.x;  // T*B = 2048
  Menc[i] = 0x007FFFFFu;                   // encf(-INFINITY)
}

// ---------- start vector: MLP + log_softmax over C ----------
__global__ void __launch_bounds__(256) k_start(
    const float* __restrict__ semb, const float* __restrict__ linW, const float* __restrict__ linb,
    const float* __restrict__ rW1, const float* __restrict__ rb1,
    const float* __restrict__ rW2, const float* __restrict__ rb2,
    const float* __restrict__ nse, float* __restrict__ startv) {
  __shared__ float sa[H], fx[H], hh[H], sl[C], red[256];
  int tid = threadIdx.x;
  sa[tid] = semb[tid];
  __syncthreads();
  float acc = linb[tid];
  for (int h = 0; h < H; ++h) acc += sa[h] * linW[tid * H + h];
  fx[tid] = acc;
  __syncthreads();
  for (int l = 0; l < 2; ++l) {
    float a1 = rb1[l * H + tid];
    const float* w1 = rW1 + (size_t)l * H * H + (size_t)tid * H;
    for (int h = 0; h < H; ++h) a1 += fx[h] * w1[h];
    hh[tid] = fmaxf(a1, 0.f);
    __syncthreads();
    float a2 = rb2[l * H + tid];
    const float* w2 = rW2 + (size_t)l * H * H + (size_t)tid * H;
    for (int h = 0; h < H; ++h) a2 += hh[h] * w2[h];
    __syncthreads();
    fx[tid] += fmaxf(a2, 0.f);
    __syncthreads();
  }
  for (int q = 0; q < 4; ++q) {
    int c = q * 256 + tid;
    const float* nr = nse + (size_t)c * H;
    float s = 0.f;
    for (int h = 0; h < H; ++h) s += fx[h] * nr[h];
    sl[c] = s;
  }
  __syncthreads();
  float m = -__builtin_inff();
  for (int q = 0; q < 4; ++q) m = fmaxf(m, sl[q * 256 + tid]);
  red[tid] = m; __syncthreads();
  for (int off = 128; off > 0; off >>= 1) { if (tid < off) red[tid] = fmaxf(red[tid], red[tid + off]); __syncthreads(); }
  m = red[0]; __syncthreads();
  float s = 0.f;
  for (int q = 0; q < 4; ++q) s += __expf(sl[q * 256 + tid] - m);
  red[tid] = s; __syncthreads();
  for (int off = 128; off > 0; off >>= 1) { if (tid < off) red[tid] += red[tid + off]; __syncthreads(); }
  float lse = m + __logf(red[0]);
  for (int q = 0; q < 4; ++q) { int c = q * 256 + tid; startv[c] = sl[c] - lse; }
}

// ---------- terminal MLP: ft = res(res(preterminal_emb)), 4 rows/block ----------
__global__ void __launch_bounds__(256) k_term_mlp(
    const float* __restrict__ pre,
    const float* __restrict__ rW1, const float* __restrict__ rb1,
    const float* __restrict__ rW2, const float* __restrict__ rb2,
    float* __restrict__ ft) {
  __shared__ float x[4][H], hh[4][H];
  int tid = threadIdx.x;
  int r0 = blockIdx.x * 4;
  for (int r = 0; r < 4; ++r) x[r][tid] = pre[(size_t)(r0 + r) * H + tid];
  __syncthreads();
  for (int l = 0; l < 2; ++l) {
    float bb = rb1[l * H + tid];
    float a0 = bb, a1 = bb, a2 = bb, a3 = bb;
    const float* w1 = rW1 + (size_t)l * H * H + (size_t)tid * H;
    for (int h = 0; h < H; ++h) {
      float w = w1[h];
      a0 += x[0][h] * w; a1 += x[1][h] * w; a2 += x[2][h] * w; a3 += x[3][h] * w;
    }
    hh[0][tid] = fmaxf(a0, 0.f); hh[1][tid] = fmaxf(a1, 0.f);
    hh[2][tid] = fmaxf(a2, 0.f); hh[3][tid] = fmaxf(a3, 0.f);
    __syncthreads();
    bb = rb2[l * H + tid];
    float b0 = bb, b1 = bb, b2 = bb, b3 = bb;
    const float* w2 = rW2 + (size_t)l * H * H + (size_t)tid * H;
    for (int h = 0; h < H; ++h) {
      float w = w2[h];
      b0 += hh[0][h] * w; b1 += hh[1][h] * w; b2 += hh[2][h] * w; b3 += hh[3][h] * w;
    }
    __syncthreads();
    x[0][tid] += fmaxf(b0, 0.f); x[1][tid] += fmaxf(b1, 0.f);
    x[2][tid] += fmaxf(b2, 0.f); x[3][tid] += fmaxf(b3, 0.f);
    __syncthreads();
  }
  for (int r = 0; r < 4; ++r) ft[(size_t)(r0 + r) * H + tid] = x[r][tid];
}

// ---------- transition: one block per row i; P^T[j][i] = softmax_j(logits+band) ----------
__global__ void __launch_bounds__(256) k_trans(
    const float* __restrict__ se, const float* __restrict__ nse,
    const float* __restrict__ band, float* __restrict__ PT) {
  __shared__ float sl[C];
  __shared__ float rr[256];
  int i = blockIdx.x;
  int tid = threadIdx.x, lane = tid & 63, w = tid >> 6;
  float4 sv = ((const float4*)(se + (size_t)i * H))[lane];
  for (int q = 0; q < 256; ++q) {
    int j = w * 256 + q;
    float4 nv = ((const float4*)(nse + (size_t)j * H))[lane];
    float p = sv.x * nv.x + sv.y * nv.y + sv.z * nv.z + sv.w * nv.w;
    #pragma unroll
    for (int off = 32; off > 0; off >>= 1) p += __shfl_xor(p, off);
    if (lane == 0) sl[j] = p;
  }
  __syncthreads();
  if (tid < K1K) {
    int col = i + tid - K;
    if (col >= 0 && col < C) sl[col] += band[(size_t)i * K1K + tid];
  }
  __syncthreads();
  float m = -__builtin_inff();
  for (int q = 0; q < 4; ++q) m = fmaxf(m, sl[q * 256 + tid]);
  rr[tid] = m; __syncthreads();
  for (int off = 128; off > 0; off >>= 1) { if (tid < off) rr[tid] = fmaxf(rr[tid], rr[tid + off]); __syncthreads(); }
  m = rr[0]; __syncthreads();
  float e[4]; float s = 0.f;
  for (int q = 0; q < 4; ++q) { e[q] = __expf(sl[q * 256 + tid] - m); s += e[q]; }
  rr[tid] = s; __syncthreads();
  for (int off = 128; off > 0; off >>= 1) { if (tid < off) rr[tid] += rr[tid + off]; __syncthreads(); }
  float inv = 1.f / rr[0];
  for (int q = 0; q < 4; ++q) {
    int j = q * 256 + tid;
    PT[(size_t)j * C + i] = e[q] * inv;
  }
}

// ---------- emission denominators: partial LSE over V chunks ----------
__global__ void __launch_bounds__(256) k_denom_part(
    const float* __restrict__ ft, const float* __restrict__ term, float* __restrict__ dpart) {
  constexpr int TJ = 16, NVC = 8, VC = V / NVC;  // 1250
  __shared__ float shm[TJ * 4], shs[TJ * 4];
  int tid = threadIdx.x, lane = tid & 63, w = tid >> 6;
  int jg = blockIdx.x >> 3, vc = blockIdx.x & 7;
  const float4* fb = (const float4*)(ft + (size_t)jg * TJ * H);
  float rm[TJ], rs[TJ];
  #pragma unroll
  for (int r = 0; r < TJ; ++r) { rm[r] = -__builtin_inff(); rs[r] = 0.f; }
  int v0 = vc * VC;
  for (int v = v0 + tid; v < v0 + VC; v += 256) {
    const float4* tr = (const float4*)(term + (size_t)v * H);
    float acc[TJ];
    #pragma unroll
    for (int r = 0; r < TJ; ++r) acc[r] = 0.f;
    for (int h4 = 0; h4 < H / 4; ++h4) {
      float4 tv = tr[h4];
      #pragma unroll
      for (int r = 0; r < TJ; ++r) {
        float4 f = fb[r * (H / 4) + h4];
        acc[r] += tv.x * f.x + tv.y * f.y + tv.z * f.z + tv.w * f.w;
      }
    }
    #pragma unroll
    for (int r = 0; r < TJ; ++r) {
      float m2 = fmaxf(rm[r], acc[r]);
      rs[r] = rs[r] * __expf(rm[r] - m2) + __expf(acc[r] - m2);
      rm[r] = m2;
    }
  }
  #pragma unroll
  for (int r = 0; r < TJ; ++r) {
    float m = rm[r], s = rs[r];
    #pragma unroll
    for (int off = 32; off > 0; off >>= 1) {
      float mo = __shfl_xor(m, off), so = __shfl_xor(s, off);
      float m2 = fmaxf(m, mo);
      s = s * __expf(m - m2) + so * __expf(mo - m2);
      m = m2;
    }
    if (lane == 0) { shm[r * 4 + w] = m; shs[r * 4 + w] = s; }
  }
  __syncthreads();
  if (tid < TJ) {
    float m = -__builtin_inff(), s = 0.f;
    for (int w2 = 0; w2 < 4; ++w2) {
      float mo = shm[tid * 4 + w2], so = shs[tid * 4 + w2];
      float m2 = fmaxf(m, mo);
      s = s * __expf(m - m2) + so * __expf(mo - m2);
      m = m2;
    }
    int j = jg * TJ + tid;
    dpart[(j * 8 + vc) * 2 + 0] = m;
    dpart[(j * 8 + vc) * 2 + 1] = s;
  }
}

__global__ void k_denom_comb(const float* __restrict__ dpart, float* __restrict__ denom) {
  int j = blockIdx.x * 256 + threadIdx.x;
  float m = -__builtin_inff(), s = 0.f;
  for (int vc = 0; vc < 8; ++vc) {
    float mo = dpart[(j * 8 + vc) * 2], so = dpart[(j * 8 + vc) * 2 + 1];
    float m2 = fmaxf(m, mo);
    s = s * __expf(m - m2) + so * __expf(mo - m2);
    m = m2;
  }
  denom[j] = m + __logf(s);
}

// ---------- emission gather: emitg[(t*B+b)*C + j] = ft[j]·term[tok] - denom[j] ----------
__global__ void __launch_bounds__(256) k_emitg(
    const int* __restrict__ text, const float* __restrict__ ft,
    const float* __restrict__ denom, const float* __restrict__ term,
    float* __restrict__ emitg) {
  int tid = threadIdx.x;
  int n0 = blockIdx.x * 8;
  const float4* trow[8];
  #pragma unroll
  for (int r = 0; r < 8; ++r) {
    int n = n0 + r;
    int tok = text[(n & 7) * T + (n >> 3)];  // text[b*T + t], n = t*B+b
    trow[r] = (const float4*)(term + (size_t)tok * H);
  }
  for (int q = 0; q < 4; ++q) {
    int j = q * 256 + tid;
    const float4* fr = (const float4*)(ft + (size_t)j * H);
    float acc[8];
    #pragma unroll
    for (int r = 0; r < 8; ++r) acc[r] = 0.f;
    for (int h4 = 0; h4 < H / 4; ++h4) {
      float4 f = fr[h4];
      #pragma unroll
      for (int r = 0; r < 8; ++r) {
        float4 tv = trow[r][h4];
        acc[r] += f.x * tv.x + f.y * tv.y + f.z * tv.z + f.w * tv.w;
      }
    }
    float dj = denom[j];
    #pragma unroll
    for (int r = 0; r < 8; ++r) emitg[(size_t)(n0 + r) * C + j] = acc[r] - dj;
  }
}

// ---------- alpha init (t=0) ----------
__global__ void k_alpha0(const float* __restrict__ startv, const float* __restrict__ emitg,
                         float* __restrict__ alpha, unsigned* __restrict__ Menc) {
  __shared__ float rr[256];
  int tid = threadIdx.x;
  int flat = blockIdx.x * 256 + tid;
  int b = flat >> 10, j = flat & 1023;
  float v = startv[j] + emitg[(size_t)b * C + j];
  alpha[flat] = v;
  rr[tid] = v; __syncthreads();
  for (int off = 128; off > 0; off >>= 1) { if (tid < off) rr[tid] = fmaxf(rr[tid], rr[tid + off]); __syncthreads(); }
  if (tid == 0) atomicMax(&Menc[b], encf(rr[0]));
}

// ---------- scan step: alpha_t = M + log(exp(alpha_{t-1}-M) @ P) + emit_t ----------
__global__ void __launch_bounds__(256) k_step(
    int t, const float* __restrict__ alpha_prev, unsigned* __restrict__ Menc,
    const float* __restrict__ PT, const float* __restrict__ emitg,
    float* __restrict__ alpha_next) {
  __shared__ float aexp[B * C];   // 32 KiB
  __shared__ float Mdec[B];
  __shared__ float wmax[4][B];
  int tid = threadIdx.x, lane = tid & 63, w = tid >> 6;
  if (tid < B) Mdec[tid] = decf(Menc[(t - 1) * B + tid]);
  __syncthreads();
  for (int k = 0; k < (B * C) / 256; ++k) {
    int idx = k * 256 + tid;
    aexp[idx] = __expf(alpha_prev[idx] - Mdec[idx >> 10]);
  }
  __syncthreads();
  int jbase = blockIdx.x * 16 + w * 4;
  const float* p0 = PT + (size_t)(jbase + 0) * C;
  const float* p1 = PT + (size_t)(jbase + 1) * C;
  const float* p2 = PT + (size_t)(jbase + 2) * C;
  const float* p3 = PT + (size_t)(jbase + 3) * C;
  float acc[4][B];
  #pragma unroll
  for (int q = 0; q < 4; ++q)
    #pragma unroll
    for (int b = 0; b < B; ++b) acc[q][b] = 0.f;
  for (int k = 0; k < 16; ++k) {
    int i = k * 64 + lane;
    float v0 = p0[i], v1 = p1[i], v2 = p2[i], v3 = p3[i];
    #pragma unroll
    for (int b = 0; b < B; ++b) {
      float a = aexp[b * C + i];
      acc[0][b] += v0 * a; acc[1][b] += v1 * a; acc[2][b] += v2 * a; acc[3][b] += v3 * a;
    }
  }
  #pragma unroll
  for (int q = 0; q < 4; ++q)
    #pragma unroll
    for (int b = 0; b < B; ++b)
      #pragma unroll
      for (int off = 32; off > 0; off >>= 1) acc[q][b] += __shfl_xor(acc[q][b], off);
  if (lane < B) {
    int b = lane;
    float M = Mdec[b];
    float vmax = -__builtin_inff();
    #pragma unroll
    for (int q = 0; q < 4; ++q) {
      int j = jbase + q;
      float val = M + __logf(acc[q][b]) + emitg[((size_t)t * B + b) * C + j];
      alpha_next[b * C + j] = val;
      vmax = fmaxf(vmax, val);
    }
    wmax[w][b] = vmax;
  }
  __syncthreads();
  if (tid < B) {
    float m = fmaxf(fmaxf(wmax[0][tid], wmax[1][tid]), fmaxf(wmax[2][tid], wmax[3][tid]));
    atomicMax(&Menc[t * B + tid], encf(m));
  }
}

// ---------- final: out[b] = logsumexp_j alpha[b,j] ----------
__global__ void k_final(const float* __restrict__ alpha, float* __restrict__ out) {
  __shared__ float rr[256];
  int tid = threadIdx.x;
  for (int b = 0; b < B; ++b) {
    const float* a = alpha + (size_t)b * C;
    float m = -__builtin_inff();
    for (int q = 0; q < 4; ++q) m = fmaxf(m, a[q * 256 + tid]);
    rr[tid] = m; __syncthreads();
    for (int off = 128; off > 0; off >>= 1) { if (tid < off) rr[tid] = fmaxf(rr[tid], rr[tid + off]); __syncthreads(); }
    m = rr[0]; __syncthreads();
    float s = 0.f;
    for (int q = 0; q < 4; ++q) s += __expf(a[q * 256 + tid] - m);
    rr[tid] = s; __syncthreads();
    for (int off = 128; off > 0; off >>= 1) { if (tid < off) rr[tid] += rr[tid + off]; __syncthreads(); }
    if (tid == 0) out[b] = m + __logf(rr[0]);
    __syncthreads();
  }
}

extern "C" void kernel_launch(void* const* d_in, const int* in_sizes, int n_in,
                              void* d_out, int out_size, void* d_ws, size_t ws_size,
                              hipStream_t stream) {
  const int*   text  = (const int*)  d_in[0];
  const float* semb  = (const float*)d_in[1];
  const float* slinW = (const float*)d_in[2];
  const float* slinb = (const float*)d_in[3];
  const float* srW1  = (const float*)d_in[4];
  const float* srb1  = (const float*)d_in[5];
  const float* srW2  = (const float*)d_in[6];
  const float* srb2  = (const float*)d_in[7];
  const float* stemb = (const float*)d_in[8];
  const float* nse   = (const float*)d_in[9];
  const float* pre   = (const float*)d_in[10];
  const float* trW1  = (const float*)d_in[11];
  const float* trb1  = (const float*)d_in[12];
  const float* trW2  = (const float*)d_in[13];
  const float* trb2  = (const float*)d_in[14];
  const float* term  = (const float*)d_in[15];
  const float* band  = (const float*)d_in[16];

  // workspace layout (floats) — total ~13.2 MiB
  float* ws     = (float*)d_ws;
  float* PT     = ws;                         // C*C
  float* emitg  = PT + (size_t)C * C;         // T*B*C
  float* alphaA = emitg + (size_t)T * B * C;  // B*C
  float* alphaB = alphaA + B * C;             // B*C
  float* ftb    = alphaB + B * C;             // C*H
  float* startv = ftb + (size_t)C * H;        // C
  float* denom  = startv + C;                 // C
  float* dpart  = denom + C;                  // C*8*2
  unsigned* Menc = (unsigned*)(dpart + C * 8 * 2);  // T*B

  k_menc_init<<<(T * B) / 256, 256, 0, stream>>>(Menc);
  k_start<<<1, 256, 0, stream>>>(semb, slinW, slinb, srW1, srb1, srW2, srb2, nse, startv);
  k_term_mlp<<<C / 4, 256, 0, stream>>>(pre, trW1, trb1, trW2, trb2, ftb);
  k_trans<<<C, 256, 0, stream>>>(stemb, nse, band, PT);
  k_denom_part<<<(C / 16) * 8, 256, 0, stream>>>(ftb, term, dpart);
  k_denom_comb<<<C / 256, 256, 0, stream>>>(dpart, denom);
  k_emitg<<<(T * B) / 8, 256, 0, stream>>>(text, ftb, denom, term, emitg);
  k_alpha0<<<(B * C) / 256, 256, 0, stream>>>(startv, emitg, alphaA, Menc);

  float* cur = alphaA;
  float* nxt = alphaB;
  for (int t = 1; t < T; ++t) {
    k_step<<<C / 16, 256, 0, stream>>>(t, cur, Menc, PT, emitg, nxt);
    float* tmp = cur; cur = nxt; nxt = tmp;
  }
  k_final<<<1, 256, 0, stream>>>(cur, (float*)d_out);
}